// Round 3
// baseline (62181.689 us; speedup 1.0000x reference)
//
#include <hip/hip_runtime.h>
#include <math.h>

#define TDIM 512
#define CCH  128      // channels
#define HW   32       // height == width
#define OCT  4        // out channels per block
#define ICT  4        // planes staged per phase per team
#define NPH  16       // phases: 16 * ICT = 64 ics per team
#define SW   40       // LDS tile row stride (36 valid + 4 pad, mult of 4)
#define SROWS 36
#define PLANE (SROWS * SW)   // 1440 floats per staged plane

// Two 256-thread teams split the input-channel reduction (split-K in block):
// team 0 -> ic 0..63, team 1 -> ic 64..127, LDS reduce, team-0 epilogue.
// EPI 0: integrate (conv(spike)*sigmoid gate -> mem_post)
// EPI 1: fire      (conv(mem_post) -> sign gate; threshold/reset; emit spikes)
template<int EPI>
__global__ __launch_bounds__(TDIM, 4) void lif_conv(
    const float* __restrict__ cin,   // conv input [B,C,32,32]
    const float* __restrict__ wgt,   // [C,C,5,5] OIHW
    const float* __restrict__ bias,  // [C]
    const float* __restrict__ aux0,  // EPI0: mem_cur ; EPI1: mem_post
    const float* __restrict__ aux1,  // EPI0: x_t     ; EPI1: unused
    float* __restrict__ out0,        // EPI0: mem_post; EPI1: mem_next
    float* __restrict__ out1,        // EPI1: spikes out[t]
    int first)
{
    const int ocg  = blockIdx.x;         // 0..31
    const int b    = blockIdx.y;         // 0..15
    const int oc0  = ocg * OCT;
    const int tid  = threadIdx.x;
    const int team = tid >> 8;           // 0/1
    const int lt   = tid & 255;
    const int rl   = lt >> 3;            // 0..31 output row
    const int cl   = (lt & 7) * 4;       // col base, 4 px/thread

    __shared__ __align__(16) float s_in[2 * ICT * PLANE];   // 46080 B
    float* tin = s_in + team * (ICT * PLANE);

    float acc[OCT][4];
#pragma unroll
    for (int oc = 0; oc < OCT; ++oc)
#pragma unroll
        for (int j = 0; j < 4; ++j) acc[oc][j] = 0.f;

    if (!(EPI == 0 && first)) {
        const int icbase = team * 64;
        // zero whole team tile once: halo stays zero across phases
        for (int i = lt; i < ICT * PLANE; i += 256) tin[i] = 0.f;

        const int sr = lt >> 3;          // staging row 0..31
        const int sg = lt & 7;           // staging col group
        float4 nv[ICT];
        // prologue: load phase 0
#pragma unroll
        for (int p = 0; p < ICT; ++p)
            nv[p] = *(const float4*)&cin[(((size_t)b * CCH + icbase + p) * HW + sr) * HW + sg * 4];
        __syncthreads();                  // zeroing visible
#pragma unroll
        for (int p = 0; p < ICT; ++p) {
            float* dst = &tin[p * PLANE + (sr + 2) * SW + 2 + sg * 4];
            *(float2*)dst       = make_float2(nv[p].x, nv[p].y);
            *(float2*)(dst + 2) = make_float2(nv[p].z, nv[p].w);
        }

        for (int ph = 0; ph < NPH; ++ph) {
            __syncthreads();              // staged phase visible
            // async prefetch next phase (hidden under compute)
            if (ph < NPH - 1) {
#pragma unroll
                for (int p = 0; p < ICT; ++p)
                    nv[p] = *(const float4*)&cin[(((size_t)b * CCH + icbase + (ph + 1) * ICT + p) * HW + sr) * HW + sg * 4];
            }
            // compute ICT input channels
#pragma unroll
            for (int ici = 0; ici < ICT; ++ici) {
                const float* wb = wgt + ((size_t)oc0 * CCH + icbase + ph * ICT + ici) * 25;
#pragma unroll
                for (int kh = 0; kh < 5; ++kh) {
                    const float* src = &tin[ici * PLANE + (rl + kh) * SW + cl];
                    float4 w0 = *(const float4*)src;
                    float4 w1 = *(const float4*)(src + 4);
                    float win[8] = {w0.x, w0.y, w0.z, w0.w, w1.x, w1.y, w1.z, w1.w};
#pragma unroll
                    for (int oc = 0; oc < OCT; ++oc) {
#pragma unroll
                        for (int kw = 0; kw < 5; ++kw) {
                            float wv = wb[oc * (CCH * 25) + kh * 5 + kw];  // wave-uniform -> s_load
                            acc[oc][0] += win[kw]     * wv;
                            acc[oc][1] += win[kw + 1] * wv;
                            acc[oc][2] += win[kw + 2] * wv;
                            acc[oc][3] += win[kw + 3] * wv;
                        }
                    }
                }
            }
            __syncthreads();              // all reads of this phase done
            if (ph < NPH - 1) {
#pragma unroll
                for (int p = 0; p < ICT; ++p) {
                    float* dst = &tin[p * PLANE + (sr + 2) * SW + 2 + sg * 4];
                    *(float2*)dst       = make_float2(nv[p].x, nv[p].y);
                    *(float2*)(dst + 2) = make_float2(nv[p].z, nv[p].w);
                }
            }
        }

        // ---- split-K reduction: team1 -> LDS (stride 17, conflict-free), team0 adds ----
        float* sred = s_in;               // reuse staging storage (17408 B)
        if (team == 1) {
#pragma unroll
            for (int oc = 0; oc < OCT; ++oc)
#pragma unroll
                for (int j = 0; j < 4; ++j)
                    sred[lt * 17 + oc * 4 + j] = acc[oc][j];
        }
        __syncthreads();
        if (team == 0) {
#pragma unroll
            for (int oc = 0; oc < OCT; ++oc)
#pragma unroll
                for (int j = 0; j < 4; ++j)
                    acc[oc][j] += sred[lt * 17 + oc * 4 + j];
        }
    }

    // ---- epilogue: fused LIF pointwise math, team 0 only, float4 I/O ----
    if (team == 0) {
#pragma unroll
        for (int oc = 0; oc < OCT; ++oc) {
            const size_t pidx = (((size_t)b * CCH + oc0 + oc) * HW + rl) * HW + cl;
            const float bia = bias[oc0 + oc];
            float y[4];
#pragma unroll
            for (int j = 0; j < 4; ++j) y[j] = acc[oc][j] + bia;
            if (EPI == 0) {
                float4 xv = *(const float4*)(aux1 + pidx);
                float4 mv;
                if (first) { mv.x = mv.y = mv.z = mv.w = 0.f; }
                else       mv = *(const float4*)(aux0 + pidx);
                float4 mp;
                mp.x = 0.2f * mv.x + (1.f / (1.f + expf(-y[0]))) * xv.x;
                mp.y = 0.2f * mv.y + (1.f / (1.f + expf(-y[1]))) * xv.y;
                mp.z = 0.2f * mv.z + (1.f / (1.f + expf(-y[2]))) * xv.z;
                mp.w = 0.2f * mv.w + (1.f / (1.f + expf(-y[3]))) * xv.w;
                *(float4*)(out0 + pidx) = mp;
            } else {
                float4 m4 = *(const float4*)(aux0 + pidx);
                float g[4] = {
                    (y[0] > 0.f) ? 1.f : ((y[0] < 0.f) ? -1.f : 0.f),
                    (y[1] > 0.f) ? 1.f : ((y[1] < 0.f) ? -1.f : 0.f),
                    (y[2] > 0.f) ? 1.f : ((y[2] < 0.f) ? -1.f : 0.f),
                    (y[3] > 0.f) ? 1.f : ((y[3] < 0.f) ? -1.f : 0.f)};
                float m[4] = {m4.x, m4.y, m4.z, m4.w};
                float4 mn, sp;
                float s0 = (m[0] > 0.5f) ? 1.f : 0.f;
                float s1 = (m[1] > 0.5f) ? 1.f : 0.f;
                float s2 = (m[2] > 0.5f) ? 1.f : 0.f;
                float s3 = (m[3] > 0.5f) ? 1.f : 0.f;
                mn.x = m[0] * (1.f - s0); sp.x = g[0] * s0;
                mn.y = m[1] * (1.f - s1); sp.y = g[1] * s1;
                mn.z = m[2] * (1.f - s2); sp.z = g[2] * s2;
                mn.w = m[3] * (1.f - s3); sp.w = g[3] * s3;
                *(float4*)(out0 + pidx) = mn;
                *(float4*)(out1 + pidx) = sp;
            }
        }
    }
}

extern "C" void kernel_launch(void* const* d_in, const int* in_sizes, int n_in,
                              void* d_out, int out_size, void* d_ws, size_t ws_size,
                              hipStream_t stream) {
    const float* x      = (const float*)d_in[0];  // [8,16,128,32,32]
    const float* back_w = (const float*)d_in[1];  // [128,128,5,5]
    const float* back_b = (const float*)d_in[2];  // [128]
    const float* ei_w   = (const float*)d_in[3];
    const float* ei_b   = (const float*)d_in[4];
    float* out = (float*)d_out;                   // [8,16,128,32,32] spikes

    const size_t N = (size_t)16 * CCH * HW * HW;  // per-timestep state elements
    float* mem_cur  = (float*)d_ws;               // ping-pong membrane (reset)
    float* mem_post = mem_cur + N;                // post-integrate membrane

    dim3 grid(CCH / OCT, 16);                     // (32, 16) = 512 blocks

    for (int t = 0; t < 8; ++t) {
        const float* spike_prev = (t == 0) ? x : (out + (size_t)(t - 1) * N);
        // integrate: mem_post = 0.2*mem + sigmoid(conv(spike_prev, back_w)+b) * x[t]
        lif_conv<0><<<grid, TDIM, 0, stream>>>(
            spike_prev, back_w, back_b,
            mem_cur, x + (size_t)t * N,
            mem_post, nullptr, (t == 0) ? 1 : 0);
        // fire: ei = sign(conv(mem_post, ei_w)+b); s = mem_post>0.5;
        //       mem_cur = mem_post*(1-s); out[t] = ei*s
        lif_conv<1><<<grid, TDIM, 0, stream>>>(
            mem_post, ei_w, ei_b,
            mem_post, nullptr,
            mem_cur, out + (size_t)t * N, 0);
    }
}

// Round 4
// 10987.552 us; speedup vs baseline: 5.6593x; 5.6593x over previous
//
#include <hip/hip_runtime.h>
#include <math.h>

#define TDIM 512
#define CCH  128      // channels
#define HW   32       // height == width
#define OCT  4        // out channels per block
#define ICT  4        // planes staged per phase per team
#define NPH  16       // phases: 16 * ICT = 64 ics per team
#define SW   40       // LDS tile row stride (36 valid + 4 pad, mult of 4)
#define SROWS 36
#define PLANE (SROWS * SW)   // 1440 floats per staged plane

// Two 256-thread teams split the input-channel reduction (split-K in block):
// team 0 -> ic 0..63, team 1 -> ic 64..127, LDS reduce, team-0 epilogue.
// CRITICAL: the team index entering WEIGHT addresses goes through
// readfirstlane so the compiler proves wave-uniformity -> s_load path.
// EPI 0: integrate (conv(spike)*sigmoid gate -> mem_post)
// EPI 1: fire      (conv(mem_post) -> sign gate; threshold/reset; emit spikes)
template<int EPI>
__global__ __launch_bounds__(TDIM, 4) void lif_conv(
    const float* __restrict__ cin,   // conv input [B,C,32,32]
    const float* __restrict__ wgt,   // [C,C,5,5] OIHW
    const float* __restrict__ bias,  // [C]
    const float* __restrict__ aux0,  // EPI0: mem_cur ; EPI1: mem_post
    const float* __restrict__ aux1,  // EPI0: x_t     ; EPI1: unused
    float* __restrict__ out0,        // EPI0: mem_post; EPI1: mem_next
    float* __restrict__ out1,        // EPI1: spikes out[t]
    int first)
{
    const int ocg  = blockIdx.x;         // 0..31
    const int b    = blockIdx.y;         // 0..15
    const int oc0  = ocg * OCT;
    const int tid  = threadIdx.x;
    const int team = tid >> 8;           // 0/1
    const int lt   = tid & 255;
    const int rl   = lt >> 3;            // 0..31 output row
    const int cl   = (lt & 7) * 4;       // col base, 4 px/thread

    // wave-uniform team index in an SGPR: weight addrs become scalar loads
    const int steam = __builtin_amdgcn_readfirstlane(team);

    __shared__ __align__(16) float s_in[2 * ICT * PLANE];   // 46080 B
    float* tin = s_in + team * (ICT * PLANE);

    float acc[OCT][4];
#pragma unroll
    for (int oc = 0; oc < OCT; ++oc)
#pragma unroll
        for (int j = 0; j < 4; ++j) acc[oc][j] = 0.f;

    if (!(EPI == 0 && first)) {
        const int icbase = team * 64;        // vector side (cin addrs: per-lane anyway)
        const int sicbase = steam * 64;      // scalar side (weight addrs)
        // zero whole team tile once: halo stays zero across phases
        for (int i = lt; i < ICT * PLANE; i += 256) tin[i] = 0.f;

        const int sr = lt >> 3;          // staging row 0..31
        const int sg = lt & 7;           // staging col group
        float4 nv[ICT];
        // prologue: load phase 0
#pragma unroll
        for (int p = 0; p < ICT; ++p)
            nv[p] = *(const float4*)&cin[(((size_t)b * CCH + icbase + p) * HW + sr) * HW + sg * 4];
        __syncthreads();                  // zeroing visible
#pragma unroll
        for (int p = 0; p < ICT; ++p) {
            float* dst = &tin[p * PLANE + (sr + 2) * SW + 2 + sg * 4];
            *(float2*)dst       = make_float2(nv[p].x, nv[p].y);
            *(float2*)(dst + 2) = make_float2(nv[p].z, nv[p].w);
        }

        for (int ph = 0; ph < NPH; ++ph) {
            __syncthreads();              // staged phase visible
            // prefetch next phase (hidden under compute)
            if (ph < NPH - 1) {
#pragma unroll
                for (int p = 0; p < ICT; ++p)
                    nv[p] = *(const float4*)&cin[(((size_t)b * CCH + icbase + (ph + 1) * ICT + p) * HW + sr) * HW + sg * 4];
            }
            // compute ICT input channels; weights via scalar loads
#pragma unroll
            for (int ici = 0; ici < ICT; ++ici) {
                const float* wb = wgt + ((size_t)oc0 * CCH + sicbase + ph * ICT + ici) * 25;
#pragma unroll
                for (int kh = 0; kh < 5; ++kh) {
                    const float* src = &tin[ici * PLANE + (rl + kh) * SW + cl];
                    float4 w0 = *(const float4*)src;
                    float4 w1 = *(const float4*)(src + 4);
                    float win[8] = {w0.x, w0.y, w0.z, w0.w, w1.x, w1.y, w1.z, w1.w};
#pragma unroll
                    for (int oc = 0; oc < OCT; ++oc) {
#pragma unroll
                        for (int kw = 0; kw < 5; ++kw) {
                            float wv = wb[oc * (CCH * 25) + kh * 5 + kw];  // SGPR-uniform -> s_load
                            acc[oc][0] += win[kw]     * wv;
                            acc[oc][1] += win[kw + 1] * wv;
                            acc[oc][2] += win[kw + 2] * wv;
                            acc[oc][3] += win[kw + 3] * wv;
                        }
                    }
                }
            }
            __syncthreads();              // all reads of this phase done
            if (ph < NPH - 1) {
#pragma unroll
                for (int p = 0; p < ICT; ++p) {
                    float* dst = &tin[p * PLANE + (sr + 2) * SW + 2 + sg * 4];
                    *(float2*)dst       = make_float2(nv[p].x, nv[p].y);
                    *(float2*)(dst + 2) = make_float2(nv[p].z, nv[p].w);
                }
            }
        }

        // ---- split-K reduction: team1 -> LDS (stride 17, conflict-free), team0 adds ----
        float* sred = s_in;               // reuse staging storage (17408 B)
        if (team == 1) {
#pragma unroll
            for (int oc = 0; oc < OCT; ++oc)
#pragma unroll
                for (int j = 0; j < 4; ++j)
                    sred[lt * 17 + oc * 4 + j] = acc[oc][j];
        }
        __syncthreads();
        if (team == 0) {
#pragma unroll
            for (int oc = 0; oc < OCT; ++oc)
#pragma unroll
                for (int j = 0; j < 4; ++j)
                    acc[oc][j] += sred[lt * 17 + oc * 4 + j];
        }
    }

    // ---- epilogue: fused LIF pointwise math, team 0 only, float4 I/O ----
    if (team == 0) {
#pragma unroll
        for (int oc = 0; oc < OCT; ++oc) {
            const size_t pidx = (((size_t)b * CCH + oc0 + oc) * HW + rl) * HW + cl;
            const float bia = bias[oc0 + oc];
            float y[4];
#pragma unroll
            for (int j = 0; j < 4; ++j) y[j] = acc[oc][j] + bia;
            if (EPI == 0) {
                float4 xv = *(const float4*)(aux1 + pidx);
                float4 mv;
                if (first) { mv.x = mv.y = mv.z = mv.w = 0.f; }
                else       mv = *(const float4*)(aux0 + pidx);
                float4 mp;
                mp.x = 0.2f * mv.x + (1.f / (1.f + expf(-y[0]))) * xv.x;
                mp.y = 0.2f * mv.y + (1.f / (1.f + expf(-y[1]))) * xv.y;
                mp.z = 0.2f * mv.z + (1.f / (1.f + expf(-y[2]))) * xv.z;
                mp.w = 0.2f * mv.w + (1.f / (1.f + expf(-y[3]))) * xv.w;
                *(float4*)(out0 + pidx) = mp;
            } else {
                float4 m4 = *(const float4*)(aux0 + pidx);
                float g[4] = {
                    (y[0] > 0.f) ? 1.f : ((y[0] < 0.f) ? -1.f : 0.f),
                    (y[1] > 0.f) ? 1.f : ((y[1] < 0.f) ? -1.f : 0.f),
                    (y[2] > 0.f) ? 1.f : ((y[2] < 0.f) ? -1.f : 0.f),
                    (y[3] > 0.f) ? 1.f : ((y[3] < 0.f) ? -1.f : 0.f)};
                float m[4] = {m4.x, m4.y, m4.z, m4.w};
                float4 mn, sp;
                float s0 = (m[0] > 0.5f) ? 1.f : 0.f;
                float s1 = (m[1] > 0.5f) ? 1.f : 0.f;
                float s2 = (m[2] > 0.5f) ? 1.f : 0.f;
                float s3 = (m[3] > 0.5f) ? 1.f : 0.f;
                mn.x = m[0] * (1.f - s0); sp.x = g[0] * s0;
                mn.y = m[1] * (1.f - s1); sp.y = g[1] * s1;
                mn.z = m[2] * (1.f - s2); sp.z = g[2] * s2;
                mn.w = m[3] * (1.f - s3); sp.w = g[3] * s3;
                *(float4*)(out0 + pidx) = mn;
                *(float4*)(out1 + pidx) = sp;
            }
        }
    }
}

extern "C" void kernel_launch(void* const* d_in, const int* in_sizes, int n_in,
                              void* d_out, int out_size, void* d_ws, size_t ws_size,
                              hipStream_t stream) {
    const float* x      = (const float*)d_in[0];  // [8,16,128,32,32]
    const float* back_w = (const float*)d_in[1];  // [128,128,5,5]
    const float* back_b = (const float*)d_in[2];  // [128]
    const float* ei_w   = (const float*)d_in[3];
    const float* ei_b   = (const float*)d_in[4];
    float* out = (float*)d_out;                   // [8,16,128,32,32] spikes

    const size_t N = (size_t)16 * CCH * HW * HW;  // per-timestep state elements
    float* mem_cur  = (float*)d_ws;               // ping-pong membrane (reset)
    float* mem_post = mem_cur + N;                // post-integrate membrane

    dim3 grid(CCH / OCT, 16);                     // (32, 16) = 512 blocks

    for (int t = 0; t < 8; ++t) {
        const float* spike_prev = (t == 0) ? x : (out + (size_t)(t - 1) * N);
        // integrate: mem_post = 0.2*mem + sigmoid(conv(spike_prev, back_w)+b) * x[t]
        lif_conv<0><<<grid, TDIM, 0, stream>>>(
            spike_prev, back_w, back_b,
            mem_cur, x + (size_t)t * N,
            mem_post, nullptr, (t == 0) ? 1 : 0);
        // fire: ei = sign(conv(mem_post, ei_w)+b); s = mem_post>0.5;
        //       mem_cur = mem_post*(1-s); out[t] = ei*s
        lif_conv<1><<<grid, TDIM, 0, stream>>>(
            mem_post, ei_w, ei_b,
            mem_post, nullptr,
            mem_cur, out + (size_t)t * N, 0);
    }
}

// Round 5
// 7726.797 us; speedup vs baseline: 8.0475x; 1.4220x over previous
//
#include <hip/hip_runtime.h>
#include <math.h>

#define TDIM 512
#define CCH  128      // channels
#define HW   32       // height == width
#define OCT  4        // out channels per block
#define ICT  4        // planes staged per phase per team
#define NPH  16       // phases: 16 * ICT = 64 ics per team
#define SW   40       // LDS tile row stride (36 valid + 4 pad, mult of 4)
#define SROWS 36
#define PLANE (SROWS * SW)   // 1440 floats per staged plane

// Two 256-thread teams split the input-channel reduction (split-K in block):
// team 0 -> ic 0..63, team 1 -> ic 64..127, LDS reduce, team-0 epilogue.
// Weight addresses go through readfirstlane -> provably wave-uniform -> s_load.
// launch_bounds min-waves/EU = 2: a 64-VGPR cap (min 4) caused massive scratch
// spills (2.2 GB WRITE_SIZE in round 4). 2 -> ~256 cap, kernel uses ~90.
// EPI 0: integrate (conv(spike)*sigmoid gate -> mem_post)
// EPI 1: fire      (conv(mem_post) -> sign gate; threshold/reset; emit spikes)
template<int EPI>
__global__ __launch_bounds__(TDIM, 2) void lif_conv(
    const float* __restrict__ cin,   // conv input [B,C,32,32]
    const float* __restrict__ wgt,   // [C,C,5,5] OIHW
    const float* __restrict__ bias,  // [C]
    const float* __restrict__ aux0,  // EPI0: mem_cur ; EPI1: mem_post
    const float* __restrict__ aux1,  // EPI0: x_t     ; EPI1: unused
    float* __restrict__ out0,        // EPI0: mem_post; EPI1: mem_next
    float* __restrict__ out1,        // EPI1: spikes out[t]
    int first)
{
    const int ocg  = blockIdx.x;         // 0..31
    const int b    = blockIdx.y;         // 0..15
    const int oc0  = ocg * OCT;
    const int tid  = threadIdx.x;
    const int team = tid >> 8;           // 0/1
    const int lt   = tid & 255;
    const int rl   = lt >> 3;            // 0..31 output row
    const int cl   = (lt & 7) * 4;       // col base, 4 px/thread

    // wave-uniform team index in an SGPR: weight addrs become scalar loads
    const int steam = __builtin_amdgcn_readfirstlane(team);

    __shared__ __align__(16) float s_in[2 * ICT * PLANE];   // 46080 B
    float* tin = s_in + team * (ICT * PLANE);

    float acc[OCT][4];
#pragma unroll
    for (int oc = 0; oc < OCT; ++oc)
#pragma unroll
        for (int j = 0; j < 4; ++j) acc[oc][j] = 0.f;

    if (!(EPI == 0 && first)) {
        const int icbase = team * 64;        // vector side (cin addrs: per-lane anyway)
        const int sicbase = steam * 64;      // scalar side (weight addrs)
        // zero whole team tile once: halo stays zero across phases
        for (int i = lt; i < ICT * PLANE; i += 256) tin[i] = 0.f;

        const int sr = lt >> 3;          // staging row 0..31
        const int sg = lt & 7;           // staging col group
        float4 nv[ICT];
        // prologue: load phase 0
#pragma unroll
        for (int p = 0; p < ICT; ++p)
            nv[p] = *(const float4*)&cin[(((size_t)b * CCH + icbase + p) * HW + sr) * HW + sg * 4];
        __syncthreads();                  // zeroing visible
#pragma unroll
        for (int p = 0; p < ICT; ++p) {
            float* dst = &tin[p * PLANE + (sr + 2) * SW + 2 + sg * 4];
            *(float2*)dst       = make_float2(nv[p].x, nv[p].y);
            *(float2*)(dst + 2) = make_float2(nv[p].z, nv[p].w);
        }

        for (int ph = 0; ph < NPH; ++ph) {
            __syncthreads();              // staged phase visible
            // prefetch next phase (hidden under compute)
            if (ph < NPH - 1) {
#pragma unroll
                for (int p = 0; p < ICT; ++p)
                    nv[p] = *(const float4*)&cin[(((size_t)b * CCH + icbase + (ph + 1) * ICT + p) * HW + sr) * HW + sg * 4];
            }
            // compute ICT input channels; weights via scalar loads
#pragma unroll
            for (int ici = 0; ici < ICT; ++ici) {
                const float* wb = wgt + ((size_t)oc0 * CCH + sicbase + ph * ICT + ici) * 25;
#pragma unroll
                for (int kh = 0; kh < 5; ++kh) {
                    const float* src = &tin[ici * PLANE + (rl + kh) * SW + cl];
                    float4 w0 = *(const float4*)src;
                    float4 w1 = *(const float4*)(src + 4);
                    float win[8] = {w0.x, w0.y, w0.z, w0.w, w1.x, w1.y, w1.z, w1.w};
#pragma unroll
                    for (int oc = 0; oc < OCT; ++oc) {
#pragma unroll
                        for (int kw = 0; kw < 5; ++kw) {
                            float wv = wb[oc * (CCH * 25) + kh * 5 + kw];  // SGPR-uniform -> s_load
                            acc[oc][0] += win[kw]     * wv;
                            acc[oc][1] += win[kw + 1] * wv;
                            acc[oc][2] += win[kw + 2] * wv;
                            acc[oc][3] += win[kw + 3] * wv;
                        }
                    }
                }
            }
            __syncthreads();              // all reads of this phase done
            if (ph < NPH - 1) {
#pragma unroll
                for (int p = 0; p < ICT; ++p) {
                    float* dst = &tin[p * PLANE + (sr + 2) * SW + 2 + sg * 4];
                    *(float2*)dst       = make_float2(nv[p].x, nv[p].y);
                    *(float2*)(dst + 2) = make_float2(nv[p].z, nv[p].w);
                }
            }
        }

        // ---- split-K reduction: team1 -> LDS (stride 17, conflict-free), team0 adds ----
        float* sred = s_in;               // reuse staging storage (17408 B)
        if (team == 1) {
#pragma unroll
            for (int oc = 0; oc < OCT; ++oc)
#pragma unroll
                for (int j = 0; j < 4; ++j)
                    sred[lt * 17 + oc * 4 + j] = acc[oc][j];
        }
        __syncthreads();
        if (team == 0) {
#pragma unroll
            for (int oc = 0; oc < OCT; ++oc)
#pragma unroll
                for (int j = 0; j < 4; ++j)
                    acc[oc][j] += sred[lt * 17 + oc * 4 + j];
        }
    }

    // ---- epilogue: fused LIF pointwise math, team 0 only, float4 I/O ----
    if (team == 0) {
#pragma unroll
        for (int oc = 0; oc < OCT; ++oc) {
            const size_t pidx = (((size_t)b * CCH + oc0 + oc) * HW + rl) * HW + cl;
            const float bia = bias[oc0 + oc];
            float y[4];
#pragma unroll
            for (int j = 0; j < 4; ++j) y[j] = acc[oc][j] + bia;
            if (EPI == 0) {
                float4 xv = *(const float4*)(aux1 + pidx);
                float4 mv;
                if (first) { mv.x = mv.y = mv.z = mv.w = 0.f; }
                else       mv = *(const float4*)(aux0 + pidx);
                float4 mp;
                mp.x = 0.2f * mv.x + (1.f / (1.f + expf(-y[0]))) * xv.x;
                mp.y = 0.2f * mv.y + (1.f / (1.f + expf(-y[1]))) * xv.y;
                mp.z = 0.2f * mv.z + (1.f / (1.f + expf(-y[2]))) * xv.z;
                mp.w = 0.2f * mv.w + (1.f / (1.f + expf(-y[3]))) * xv.w;
                *(float4*)(out0 + pidx) = mp;
            } else {
                float4 m4 = *(const float4*)(aux0 + pidx);
                float g[4] = {
                    (y[0] > 0.f) ? 1.f : ((y[0] < 0.f) ? -1.f : 0.f),
                    (y[1] > 0.f) ? 1.f : ((y[1] < 0.f) ? -1.f : 0.f),
                    (y[2] > 0.f) ? 1.f : ((y[2] < 0.f) ? -1.f : 0.f),
                    (y[3] > 0.f) ? 1.f : ((y[3] < 0.f) ? -1.f : 0.f)};
                float m[4] = {m4.x, m4.y, m4.z, m4.w};
                float4 mn, sp;
                float s0 = (m[0] > 0.5f) ? 1.f : 0.f;
                float s1 = (m[1] > 0.5f) ? 1.f : 0.f;
                float s2 = (m[2] > 0.5f) ? 1.f : 0.f;
                float s3 = (m[3] > 0.5f) ? 1.f : 0.f;
                mn.x = m[0] * (1.f - s0); sp.x = g[0] * s0;
                mn.y = m[1] * (1.f - s1); sp.y = g[1] * s1;
                mn.z = m[2] * (1.f - s2); sp.z = g[2] * s2;
                mn.w = m[3] * (1.f - s3); sp.w = g[3] * s3;
                *(float4*)(out0 + pidx) = mn;
                *(float4*)(out1 + pidx) = sp;
            }
        }
    }
}

extern "C" void kernel_launch(void* const* d_in, const int* in_sizes, int n_in,
                              void* d_out, int out_size, void* d_ws, size_t ws_size,
                              hipStream_t stream) {
    const float* x      = (const float*)d_in[0];  // [8,16,128,32,32]
    const float* back_w = (const float*)d_in[1];  // [128,128,5,5]
    const float* back_b = (const float*)d_in[2];  // [128]
    const float* ei_w   = (const float*)d_in[3];
    const float* ei_b   = (const float*)d_in[4];
    float* out = (float*)d_out;                   // [8,16,128,32,32] spikes

    const size_t N = (size_t)16 * CCH * HW * HW;  // per-timestep state elements
    float* mem_cur  = (float*)d_ws;               // ping-pong membrane (reset)
    float* mem_post = mem_cur + N;                // post-integrate membrane

    dim3 grid(CCH / OCT, 16);                     // (32, 16) = 512 blocks

    for (int t = 0; t < 8; ++t) {
        const float* spike_prev = (t == 0) ? x : (out + (size_t)(t - 1) * N);
        // integrate: mem_post = 0.2*mem + sigmoid(conv(spike_prev, back_w)+b) * x[t]
        lif_conv<0><<<grid, TDIM, 0, stream>>>(
            spike_prev, back_w, back_b,
            mem_cur, x + (size_t)t * N,
            mem_post, nullptr, (t == 0) ? 1 : 0);
        // fire: ei = sign(conv(mem_post, ei_w)+b); s = mem_post>0.5;
        //       mem_cur = mem_post*(1-s); out[t] = ei*s
        lif_conv<1><<<grid, TDIM, 0, stream>>>(
            mem_post, ei_w, ei_b,
            mem_post, nullptr,
            mem_cur, out + (size_t)t * N, 0);
    }
}

// Round 6
// 2127.000 us; speedup vs baseline: 29.2345x; 3.6327x over previous
//
#include <hip/hip_runtime.h>
#include <math.h>

#define TDIM 512
#define CCH  128      // channels
#define HW   32       // height == width
#define OCT  4        // out channels per block
#define ICT  4        // planes staged per phase per team
#define NPH  16       // phases: 16 * ICT = 64 ics per team
#define SW   36       // LDS row stride: 144B = 9*16B (b128-aligned), 36%32=4 -> conflict-free rows
#define SROWS 36
#define PLANE (SROWS * SW)   // 1296 floats per staged plane

// Two 256-thread teams split the input-channel reduction (split-K in block):
// team 0 -> ic 0..63, team 1 -> ic 64..127, LDS reduce, team-0 epilogue.
// Weight addresses go through readfirstlane -> provably wave-uniform -> s_load.
// NO cross-phase register prefetch: it cost 16 held VGPRs -> spills at the
// 128-VGPR cap (round 5: 40MB scratch WRITE_SIZE). Staging latency is hidden
// by the other independent block on the CU (2 blocks/CU).
// EPI 0: integrate (conv(spike)*sigmoid gate -> mem_post)
// EPI 1: fire      (conv(mem_post) -> sign gate; threshold/reset; emit spikes)
template<int EPI>
__global__ __launch_bounds__(TDIM, 2) void lif_conv(
    const float* __restrict__ cin,   // conv input [B,C,32,32]
    const float* __restrict__ wgt,   // [C,C,5,5] OIHW
    const float* __restrict__ bias,  // [C]
    const float* __restrict__ aux0,  // EPI0: mem_cur ; EPI1: mem_post
    const float* __restrict__ aux1,  // EPI0: x_t     ; EPI1: unused
    float* __restrict__ out0,        // EPI0: mem_post; EPI1: mem_next
    float* __restrict__ out1,        // EPI1: spikes out[t]
    int first)
{
    const int ocg  = blockIdx.x;         // 0..31
    const int b    = blockIdx.y;         // 0..15
    const int oc0  = ocg * OCT;
    const int tid  = threadIdx.x;
    const int team = tid >> 8;           // 0/1
    const int lt   = tid & 255;
    const int rl   = lt >> 3;            // 0..31 output row
    const int cl   = (lt & 7) * 4;       // col base, 4 px/thread

    // wave-uniform team index in an SGPR: weight addrs become scalar loads
    const int steam = __builtin_amdgcn_readfirstlane(team);

    __shared__ __align__(16) float s_in[2 * ICT * PLANE];   // 41472 B
    float* tin = s_in + team * (ICT * PLANE);

    float acc[OCT][4];
#pragma unroll
    for (int oc = 0; oc < OCT; ++oc)
#pragma unroll
        for (int j = 0; j < 4; ++j) acc[oc][j] = 0.f;

    if (!(EPI == 0 && first)) {
        const int icbase  = team * 64;       // vector side (cin addrs: per-lane anyway)
        const int sicbase = steam * 64;      // scalar side (weight addrs)
        // zero whole team tile once: halo stays zero across phases
        for (int i = lt; i < ICT * PLANE; i += 256) tin[i] = 0.f;
        __syncthreads();                     // zeroing visible

        const int sr = lt >> 3;          // staging row 0..31
        const int sg = lt & 7;           // staging col group

        for (int ph = 0; ph < NPH; ++ph) {
            // ---- stage ICT interior planes (sync, hidden by other block) ----
#pragma unroll
            for (int p = 0; p < ICT; ++p) {
                float4 v = *(const float4*)&cin[(((size_t)b * CCH + icbase + ph * ICT + p) * HW + sr) * HW + sg * 4];
                float* dst = &tin[p * PLANE + (sr + 2) * SW + 2 + sg * 4];
                *(float2*)dst       = make_float2(v.x, v.y);
                *(float2*)(dst + 2) = make_float2(v.z, v.w);
            }
            __syncthreads();              // staged phase visible
            // ---- compute ICT input channels; weights via scalar loads ----
#pragma unroll
            for (int ici = 0; ici < ICT; ++ici) {
                const float* wb = wgt + ((size_t)oc0 * CCH + sicbase + ph * ICT + ici) * 25;
#pragma unroll
                for (int kh = 0; kh < 5; ++kh) {
                    const float* src = &tin[ici * PLANE + (rl + kh) * SW + cl];
                    float4 w0 = *(const float4*)src;
                    float4 w1 = *(const float4*)(src + 4);
                    float win[8] = {w0.x, w0.y, w0.z, w0.w, w1.x, w1.y, w1.z, w1.w};
#pragma unroll
                    for (int oc = 0; oc < OCT; ++oc) {
#pragma unroll
                        for (int kw = 0; kw < 5; ++kw) {
                            float wv = wb[oc * (CCH * 25) + kh * 5 + kw];  // SGPR-uniform -> s_load
                            acc[oc][0] += win[kw]     * wv;
                            acc[oc][1] += win[kw + 1] * wv;
                            acc[oc][2] += win[kw + 2] * wv;
                            acc[oc][3] += win[kw + 3] * wv;
                        }
                    }
                }
            }
            __syncthreads();              // all reads of this phase done before restage
        }

        // ---- split-K reduction: team1 -> LDS (stride 17, conflict-free), team0 adds ----
        float* sred = s_in;               // reuse staging storage (17408 B)
        if (team == 1) {
#pragma unroll
            for (int oc = 0; oc < OCT; ++oc)
#pragma unroll
                for (int j = 0; j < 4; ++j)
                    sred[lt * 17 + oc * 4 + j] = acc[oc][j];
        }
        __syncthreads();
        if (team == 0) {
#pragma unroll
            for (int oc = 0; oc < OCT; ++oc)
#pragma unroll
                for (int j = 0; j < 4; ++j)
                    acc[oc][j] += sred[lt * 17 + oc * 4 + j];
        }
    }

    // ---- epilogue: fused LIF pointwise math, team 0 only, float4 I/O ----
    if (team == 0) {
#pragma unroll
        for (int oc = 0; oc < OCT; ++oc) {
            const size_t pidx = (((size_t)b * CCH + oc0 + oc) * HW + rl) * HW + cl;
            const float bia = bias[oc0 + oc];
            float y[4];
#pragma unroll
            for (int j = 0; j < 4; ++j) y[j] = acc[oc][j] + bia;
            if (EPI == 0) {
                float4 xv = *(const float4*)(aux1 + pidx);
                float4 mv;
                if (first) { mv.x = mv.y = mv.z = mv.w = 0.f; }
                else       mv = *(const float4*)(aux0 + pidx);
                float4 mp;
                mp.x = 0.2f * mv.x + (1.f / (1.f + expf(-y[0]))) * xv.x;
                mp.y = 0.2f * mv.y + (1.f / (1.f + expf(-y[1]))) * xv.y;
                mp.z = 0.2f * mv.z + (1.f / (1.f + expf(-y[2]))) * xv.z;
                mp.w = 0.2f * mv.w + (1.f / (1.f + expf(-y[3]))) * xv.w;
                *(float4*)(out0 + pidx) = mp;
            } else {
                float4 m4 = *(const float4*)(aux0 + pidx);
                float g[4] = {
                    (y[0] > 0.f) ? 1.f : ((y[0] < 0.f) ? -1.f : 0.f),
                    (y[1] > 0.f) ? 1.f : ((y[1] < 0.f) ? -1.f : 0.f),
                    (y[2] > 0.f) ? 1.f : ((y[2] < 0.f) ? -1.f : 0.f),
                    (y[3] > 0.f) ? 1.f : ((y[3] < 0.f) ? -1.f : 0.f)};
                float m[4] = {m4.x, m4.y, m4.z, m4.w};
                float4 mn, sp;
                float s0 = (m[0] > 0.5f) ? 1.f : 0.f;
                float s1 = (m[1] > 0.5f) ? 1.f : 0.f;
                float s2 = (m[2] > 0.5f) ? 1.f : 0.f;
                float s3 = (m[3] > 0.5f) ? 1.f : 0.f;
                mn.x = m[0] * (1.f - s0); sp.x = g[0] * s0;
                mn.y = m[1] * (1.f - s1); sp.y = g[1] * s1;
                mn.z = m[2] * (1.f - s2); sp.z = g[2] * s2;
                mn.w = m[3] * (1.f - s3); sp.w = g[3] * s3;
                *(float4*)(out0 + pidx) = mn;
                *(float4*)(out1 + pidx) = sp;
            }
        }
    }
}

extern "C" void kernel_launch(void* const* d_in, const int* in_sizes, int n_in,
                              void* d_out, int out_size, void* d_ws, size_t ws_size,
                              hipStream_t stream) {
    const float* x      = (const float*)d_in[0];  // [8,16,128,32,32]
    const float* back_w = (const float*)d_in[1];  // [128,128,5,5]
    const float* back_b = (const float*)d_in[2];  // [128]
    const float* ei_w   = (const float*)d_in[3];
    const float* ei_b   = (const float*)d_in[4];
    float* out = (float*)d_out;                   // [8,16,128,32,32] spikes

    const size_t N = (size_t)16 * CCH * HW * HW;  // per-timestep state elements
    float* mem_cur  = (float*)d_ws;               // ping-pong membrane (reset)
    float* mem_post = mem_cur + N;                // post-integrate membrane

    dim3 grid(CCH / OCT, 16);                     // (32, 16) = 512 blocks

    for (int t = 0; t < 8; ++t) {
        const float* spike_prev = (t == 0) ? x : (out + (size_t)(t - 1) * N);
        // integrate: mem_post = 0.2*mem + sigmoid(conv(spike_prev, back_w)+b) * x[t]
        lif_conv<0><<<grid, TDIM, 0, stream>>>(
            spike_prev, back_w, back_b,
            mem_cur, x + (size_t)t * N,
            mem_post, nullptr, (t == 0) ? 1 : 0);
        // fire: ei = sign(conv(mem_post, ei_w)+b); s = mem_post>0.5;
        //       mem_cur = mem_post*(1-s); out[t] = ei*s
        lif_conv<1><<<grid, TDIM, 0, stream>>>(
            mem_post, ei_w, ei_b,
            mem_post, nullptr,
            mem_cur, out + (size_t)t * N, 0);
    }
}